// Round 2
// baseline (290.771 us; speedup 1.0000x reference)
//
#include <hip/hip_runtime.h>

#define B_ 16
#define K_ 20
#define H_ 256
#define W_ 256
#define HW_ (H_*W_)
#define BK_ (B_*K_)
#define S_ 16        // strip rows per wave in fused
#define NSTRIP_ 16   // H_/S_

__device__ __forceinline__ float4 ld4(const float* p) { return *(const float4*)p; }
__device__ __forceinline__ float4 zero4() { return make_float4(0.f, 0.f, 0.f, 0.f); }

// exp(-(j-4)^2/50), j=0..8 (separable 2D gaussian: exp(-(di^2+dj^2)/50))
#define G0_ 0.72614903707f
#define G1_ 0.83527021141f
#define G2_ 0.92311634639f
#define G3_ 0.98019867331f

__global__ __launch_bounds__(256) void zero_ws_k(float* ws, int n) {
    int i = blockIdx.x * 256 + threadIdx.x;
    if (i < n) ws[i] = 0.f;
}

// Per-(b,k): sum(labels), sum(labels*inputs_c). One block = one (b,k,16-row chunk).
// XCD swizzle: all K blocks sharing (b,chunk) have equal blockIdx%8 -> same XCD L2.
__global__ __launch_bounds__(256) void stats_k(const float* __restrict__ labels,
                                               const float* __restrict__ inputs,
                                               float* __restrict__ sums) {
    int idx = blockIdx.x;
    int low = idx & 7; int t1 = idx >> 3;
    int k = t1 % K_; int bch = t1 / K_;
    int bc = bch * 8 + low;          // bc = chunk + 16*b, in [0,256)
    int chunk = bc & 15, b = bc >> 4;

    int tid = threadIdx.x;
    int rowi = tid >> 6;             // 4 rows in flight per iteration
    int colo = (tid & 63) * 4;

    const float* lrow = labels + ((size_t)(b * K_ + k)) * HW_;
    const float* ip   = inputs + (size_t)b * 3 * HW_;

    float sl = 0.f, s0 = 0.f, s1 = 0.f, s2 = 0.f;
    int r0 = chunk * 16 + rowi;
#pragma unroll
    for (int it = 0; it < 4; ++it) {
        int off = (r0 + it * 4) * W_ + colo;
        float4 l  = ld4(lrow + off);
        float4 a  = ld4(ip + off);
        float4 bb = ld4(ip + HW_ + off);
        float4 cc = ld4(ip + 2 * HW_ + off);
        sl += (l.x + l.y) + (l.z + l.w);
        s0 += l.x * a.x  + l.y * a.y  + l.z * a.z  + l.w * a.w;
        s1 += l.x * bb.x + l.y * bb.y + l.z * bb.z + l.w * bb.w;
        s2 += l.x * cc.x + l.y * cc.y + l.z * cc.z + l.w * cc.w;
    }
#pragma unroll
    for (int o = 32; o > 0; o >>= 1) {
        sl += __shfl_xor(sl, o); s0 += __shfl_xor(s0, o);
        s1 += __shfl_xor(s1, o); s2 += __shfl_xor(s2, o);
    }
    __shared__ float rb[4][4];
    int wv = tid >> 6, lane = tid & 63;
    if (lane == 0) { rb[0][wv] = sl; rb[1][wv] = s0; rb[2][wv] = s1; rb[3][wv] = s2; }
    __syncthreads();
    if (tid == 0) {
        int bk = b * K_ + k;
        atomicAdd(&sums[bk],          rb[0][0] + rb[0][1] + rb[0][2] + rb[0][3]);
        atomicAdd(&sums[BK_ + bk],    rb[1][0] + rb[1][1] + rb[1][2] + rb[1][3]);
        atomicAdd(&sums[2*BK_ + bk],  rb[2][0] + rb[2][1] + rb[2][2] + rb[2][3]);
        atomicAdd(&sums[3*BK_ + bk],  rb[3][0] + rb[3][1] + rb[3][2] + rb[3][3]);
    }
}

__device__ __forceinline__ float4 hblur9(float4 vL, float4 v, float4 vR) {
    const float G[9] = {G0_, G1_, G2_, G3_, 1.0f, G3_, G2_, G1_, G0_};
    float w[12] = {vL.x, vL.y, vL.z, vL.w, v.x, v.y, v.z, v.w, vR.x, vR.y, vR.z, vR.w};
    float4 o = zero4();
#pragma unroll
    for (int j = 0; j < 9; ++j) {
        o.x += G[j] * w[j];     o.y += G[j] * w[j + 1];
        o.z += G[j] * w[j + 2]; o.w += G[j] * w[j + 3];
    }
    return o;
}

// One wave = one (b, k, 16-row strip). Lane holds 4 cols (float4); 64 lanes = full row.
// Horizontal blur via shuffles (no LDS, no syncthreads); vertical via static %9 ring.
__global__ __launch_bounds__(256) void fused_k(const float* __restrict__ labels,
                                               const float* __restrict__ inputs,
                                               const float* __restrict__ sums,
                                               float* __restrict__ numden) {
    const float G[9] = {G0_, G1_, G2_, G3_, 1.0f, G3_, G2_, G1_, G0_};
    int idx = blockIdx.x;
    int low = idx & 7; int t1 = idx >> 3;
    int kq = t1 % 5; int sbh = t1 / 5;
    int sb = sbh * 8 + low;          // sb = strip + 16*b; same (strip,b) -> same XCD
    int strip = sb & 15, b = sb >> 4;
    int tid = threadIdx.x;
    int lane = tid & 63, wv = tid >> 6;
    int k = kq * 4 + wv;             // 4 waves in block share input rows (L1 reuse)
    int bk = b * K_ + k;

    float dn  = sums[bk] + 1e-5f * (float)HW_;
    float inv = 1.f / dn;
    float cm0 = sums[BK_ + bk] * inv;
    float cm1 = sums[2 * BK_ + bk] * inv;
    float cm2 = sums[3 * BK_ + bk] * inv;
    float m2  = cm0 * cm0 + cm1 * cm1 + cm2 * cm2;

    const float* lrow = labels + (size_t)bk * HW_;
    const float* i0p = inputs + (size_t)b * 3 * HW_;
    const float* i1p = i0p + HW_;
    const float* i2p = i0p + 2 * HW_;
    const int colo = lane * 4;
    const int r0 = strip * S_;

    float4 hwr[9], hlr[9];   // horizontally-blurred w and l*w rows (ring)

    auto loadrow = [&](int t, float4& ohw, float4& ohl) {
        if ((unsigned)t < (unsigned)H_) {
            int off = t * W_ + colo;
            float4 l  = ld4(lrow + off);
            float4 a  = ld4(i0p + off);
            float4 bb = ld4(i1p + off);
            float4 cc = ld4(i2p + off);
            float4 w4, lw4;
            {
                float x2 = a.x*a.x + bb.x*bb.x + cc.x*cc.x;
                float cr = a.x*cm0 + bb.x*cm1 + cc.x*cm2;
                float df = x2 - 2.f*cr + m2;
                w4.x = __expf(-(df*df)); lw4.x = l.x * w4.x;
            }
            {
                float x2 = a.y*a.y + bb.y*bb.y + cc.y*cc.y;
                float cr = a.y*cm0 + bb.y*cm1 + cc.y*cm2;
                float df = x2 - 2.f*cr + m2;
                w4.y = __expf(-(df*df)); lw4.y = l.y * w4.y;
            }
            {
                float x2 = a.z*a.z + bb.z*bb.z + cc.z*cc.z;
                float cr = a.z*cm0 + bb.z*cm1 + cc.z*cm2;
                float df = x2 - 2.f*cr + m2;
                w4.z = __expf(-(df*df)); lw4.z = l.z * w4.z;
            }
            {
                float x2 = a.w*a.w + bb.w*bb.w + cc.w*cc.w;
                float cr = a.w*cm0 + bb.w*cm1 + cc.w*cm2;
                float df = x2 - 2.f*cr + m2;
                w4.w = __expf(-(df*df)); lw4.w = l.w * w4.w;
            }
            // neighbor halos via cross-lane shuffles (wave = full row)
            float4 wl, wr2, ll2, lr2;
            wl.x  = __shfl_up(w4.x, 1);  wl.y  = __shfl_up(w4.y, 1);
            wl.z  = __shfl_up(w4.z, 1);  wl.w  = __shfl_up(w4.w, 1);
            wr2.x = __shfl_down(w4.x, 1); wr2.y = __shfl_down(w4.y, 1);
            wr2.z = __shfl_down(w4.z, 1); wr2.w = __shfl_down(w4.w, 1);
            ll2.x = __shfl_up(lw4.x, 1); ll2.y = __shfl_up(lw4.y, 1);
            ll2.z = __shfl_up(lw4.z, 1); ll2.w = __shfl_up(lw4.w, 1);
            lr2.x = __shfl_down(lw4.x, 1); lr2.y = __shfl_down(lw4.y, 1);
            lr2.z = __shfl_down(lw4.z, 1); lr2.w = __shfl_down(lw4.w, 1);
            if (lane == 0)  { wl  = zero4(); ll2 = zero4(); }
            if (lane == 63) { wr2 = zero4(); lr2 = zero4(); }
            ohw = hblur9(wl, w4, wr2);
            ohl = hblur9(ll2, lw4, lr2);
        } else {
            ohw = zero4(); ohl = zero4();
        }
    };

#pragma unroll
    for (int i = 0; i < 8; ++i) loadrow(r0 - 4 + i, hwr[i], hlr[i]);

    float nx=0,ny=0,nz=0,nw=0, dx=0,dy=0,dz=0,dw=0;
#pragma unroll
    for (int rr = 0; rr < S_; ++rr) {
        loadrow(r0 + rr + 4, hwr[(rr + 8) % 9], hlr[(rr + 8) % 9]);
        float4 vw = zero4(), vl = zero4();
#pragma unroll
        for (int j = 0; j < 9; ++j) {
            const float4& aw = hwr[(rr + j) % 9];
            const float4& al = hlr[(rr + j) % 9];
            vw.x += G[j]*aw.x; vw.y += G[j]*aw.y; vw.z += G[j]*aw.z; vw.w += G[j]*aw.w;
            vl.x += G[j]*al.x; vl.y += G[j]*al.y; vl.z += G[j]*al.z; vl.w += G[j]*al.w;
        }
        float4 l = ld4(lrow + (r0 + rr) * W_ + colo);  // center row (L1/L2 hit)
        nx += l.x*vl.x; ny += l.y*vl.y; nz += l.z*vl.z; nw += l.w*vl.w;
        dx += l.x*vw.x; dy += l.y*vw.y; dz += l.z*vw.z; dw += l.w*vw.w;
    }
    float num = (nx + ny) + (nz + nw);
    float den = (dx + dy) + (dz + dw);
#pragma unroll
    for (int o = 32; o > 0; o >>= 1) { num += __shfl_xor(num, o); den += __shfl_xor(den, o); }
    if (lane == 0) {
        atomicAdd(&numden[k], num);
        atomicAdd(&numden[K_ + k], den);
    }
}

__global__ void finalize_k(const float* __restrict__ numden, float* __restrict__ out) {
    if (threadIdx.x == 0 && blockIdx.x == 0) {
        float loss = 0.f;
        for (int kk = 0; kk < K_; ++kk)
            loss += fabsf(numden[kk] / (numden[K_ + kk] + 1e-6f));
        out[0] = (float)K_ - loss;
    }
}

extern "C" void kernel_launch(void* const* d_in, const int* in_sizes, int n_in,
                              void* d_out, int out_size, void* d_ws, size_t ws_size,
                              hipStream_t stream) {
    const float* labels = (const float*)d_in[0];
    const float* inputs = (const float*)d_in[1];
    float* ws     = (float*)d_ws;
    float* sums   = ws;                 // 4 * B * K floats
    float* numden = ws + 4 * BK_;       // 2 * K floats
    const int nz = 4 * BK_ + 2 * K_;

    zero_ws_k<<<(nz + 255) / 256, 256, 0, stream>>>(ws, nz);
    stats_k<<<256 * K_, 256, 0, stream>>>(labels, inputs, sums);          // 5120 blocks
    fused_k<<<(NSTRIP_ * B_ * 5), 256, 0, stream>>>(labels, inputs, sums, numden); // 1280 blocks
    finalize_k<<<1, 64, 0, stream>>>(numden, (float*)d_out);
}